// Round 13
// baseline (269.431 us; speedup 1.0000x reference)
//
#include <hip/hip_runtime.h>

typedef unsigned short u16;
typedef short bf16x8 __attribute__((ext_vector_type(8)));
typedef float f32x4 __attribute__((ext_vector_type(4)));

// B=4, S=2048, E=1024, H=16, dk=64
#define SEQ   2048
#define EMB   1024
#define NH    16
#define DK    64

// softmax in base-2: Q path pre-scaled by 0.125 * log2(e)  (baked into WQt)
#define QSCALE 0.1803368801111144f

__device__ __forceinline__ u16 bf16_rne(float f) {
  union { float f; unsigned u; } x;
  x.f = f;
  unsigned u = x.u;
  u += 0x7fffu + ((u >> 16) & 1u);
  return (u16)(u >> 16);
}

// packed f32x2 -> bf16x2 (lo = a, hi = b), 1 VALU op
__device__ __forceinline__ unsigned cvt_pk_bf16(float a, float b) {
  unsigned r;
  asm("v_cvt_pk_bf16_f32 %0, %1, %2" : "=v"(r) : "v"(a), "v"(b));
  return r;
}

// raw v_exp_f32: D = 2^S0 (single instruction; libm exp2f adds range fixup)
__device__ __forceinline__ float exp2_raw(float x) {
#if __has_builtin(__builtin_amdgcn_exp2f)
  return __builtin_amdgcn_exp2f(x);
#else
  float r; asm("v_exp_f32 %0, %1" : "=v"(r) : "v"(x)); return r;
#endif
}

// Redistribute packed P words into the PV A-fragment, all on the VALU pipe.
__device__ __forceinline__ bf16x8 pfrag(unsigned x0, unsigned y0,
                                        unsigned x1, unsigned y1) {
  asm("v_permlane32_swap_b32 %0, %1" : "+v"(x0), "+v"(x1));
  asm("v_permlane32_swap_b32 %0, %1" : "+v"(y0), "+v"(y1));
  asm("v_permlane16_swap_b32 %0, %1" : "+v"(x0), "+v"(x1));
  asm("v_permlane16_swap_b32 %0, %1" : "+v"(y0), "+v"(y1));
  union { unsigned u[4]; bf16x8 v; } f;
  f.u[0] = x0; f.u[1] = y0; f.u[2] = x1; f.u[3] = y1;
  return f.v;
}

#define GLD(src, dst)                                                         \
  __builtin_amdgcn_global_load_lds(                                           \
      (const __attribute__((address_space(1))) void*)(src),                   \
      (__attribute__((address_space(3))) void*)(dst), 16, 0, 0)

// ---------------------------------------------------------------- fallback
__global__ __launch_bounds__(256) void fill_sig(float* __restrict__ out, int n) {
  const int i = blockIdx.x * 256 + threadIdx.x;
  if (i < n) out[i] = 1.0f;   // "workspace too small" signal
}

// ---------------------------------------------------------------- x -> bf16
__global__ __launch_bounds__(256) void cvt_x(const float* __restrict__ x,
                                             u16* __restrict__ xb) {
  const size_t i = ((size_t)blockIdx.x * 256 + threadIdx.x) * 8;
  float4 v0 = *(const float4*)(x + i);
  float4 v1 = *(const float4*)(x + i + 4);
  union { int4 v; u16 h[8]; } c;
  c.h[0] = bf16_rne(v0.x); c.h[1] = bf16_rne(v0.y);
  c.h[2] = bf16_rne(v0.z); c.h[3] = bf16_rne(v0.w);
  c.h[4] = bf16_rne(v1.x); c.h[5] = bf16_rne(v1.y);
  c.h[6] = bf16_rne(v1.z); c.h[7] = bf16_rne(v1.w);
  *(int4*)(xb + i) = c.v;
}

// ---------------------------------------------------------------- transpose+convert
__global__ __launch_bounds__(256) void tcvt3(
    const float* __restrict__ s0, const float* __restrict__ s1, const float* __restrict__ s2,
    u16* __restrict__ d0, u16* __restrict__ d1, u16* __restrict__ d2) {
  const int z = blockIdx.z;
  const float* src = (z == 0) ? s0 : (z == 1) ? s1 : s2;
  u16* dst = (z == 0) ? d0 : (z == 1) ? d1 : d2;
  const float sc = (z == 0) ? QSCALE : 1.0f;
  __shared__ u16 tile[64][65];
  const int bx = blockIdx.x * 64, by = blockIdx.y * 64;
  for (int i = threadIdx.x; i < 64 * 64; i += 256) {
    const int r = i >> 6, c = i & 63;
    tile[c][r] = bf16_rne(src[(size_t)(by + r) * EMB + bx + c] * sc);
  }
  __syncthreads();
  for (int i = threadIdx.x; i < 64 * 64; i += 256) {
    const int r = i >> 6, c = i & 63;
    dst[(size_t)(bx + r) * EMB + by + c] = tile[r][c];
  }
}

__global__ __launch_bounds__(256) void tcvt1(const float* __restrict__ src,
                                             u16* __restrict__ dst) {
  __shared__ u16 tile[64][65];
  const int bx = blockIdx.x * 64, by = blockIdx.y * 64;
  for (int i = threadIdx.x; i < 64 * 64; i += 256) {
    const int r = i >> 6, c = i & 63;
    tile[c][r] = bf16_rne(src[(size_t)(by + r) * EMB + bx + c]);
  }
  __syncthreads();
  for (int i = threadIdx.x; i < 64 * 64; i += 256) {
    const int r = i >> 6, c = i & 63;
    dst[(size_t)(bx + r) * EMB + by + c] = tile[r][c];
  }
}

// ---------------------------------------------------------------- QKV GEMM
// R13: BK=128 in the proven single-buffer 2-barrier schedule (8 K-steps,
// 64 MFMA/wave per step). 16-slot XOR swizzle: physical slot s of row R holds
// logical s ^ (R&15); staging keeps the LINEAR gload_lds dest
// (As + i*2048 + tid*8) and pre-swizzles the global source column; fragment
// reads XOR the slot with l15 -> all 8 bank-quads x 2 lanes (conflict-free).
__global__ __launch_bounds__(256) void gemm_qkv(
    const u16* __restrict__ A,
    const u16* __restrict__ T0, const u16* __restrict__ T1, const u16* __restrict__ T2,
    u16* __restrict__ C0, u16* __restrict__ C1, u16* __restrict__ C2)
{
  const int z = blockIdx.z;
  const u16* Wt = (z == 0) ? T0 : (z == 1) ? T1 : T2;
  u16* C = (z == 0) ? C0 : (z == 1) ? C1 : C2;

  __shared__ __align__(16) u16 sh[32768];  // As 16384 + Bs 16384 (BK=128)
  u16* const As = sh;
  u16* const Bs = sh + 16384;

  const int tid  = threadIdx.x;
  const int lane = tid & 63;
  const int w    = tid >> 6;
  const int wm   = (w >> 1) * 64;
  const int wn   = (w & 1) * 64;
  const int m0   = blockIdx.x * 128;
  const int n0   = blockIdx.y * 128;

  const int l15  = lane & 15;
  const int g    = lane >> 4;

  const int grow = tid >> 4;                       // 0..15: row within 16-row chunk
  const int gcol = ((tid & 15) ^ grow) * 8;        // pre-swizzled source col (u16)

  const u16* const gaB = A  + (size_t)(m0 + grow) * 1024 + gcol;
  const u16* const gbB = Wt + (size_t)(n0 + grow) * 1024 + gcol;

  f32x4 acc[4][4] = {};

  for (int k0 = 0; k0 < 1024; k0 += 128) {
#pragma unroll
    for (int i = 0; i < 8; ++i) {
      GLD(gaB + (size_t)i * 16 * 1024 + k0, As + i * 2048 + tid * 8);
      GLD(gbB + (size_t)i * 16 * 1024 + k0, Bs + i * 2048 + tid * 8);
    }
    __syncthreads();
#pragma unroll
    for (int kk = 0; kk < 4; ++kk) {
      const int so = ((kk * 4 + g) ^ l15) * 8;
      bf16x8 a[4], b[4];
#pragma unroll
      for (int mi = 0; mi < 4; ++mi)
        a[mi] = *(const bf16x8*)(As + (wm + mi * 16 + l15) * 128 + so);
#pragma unroll
      for (int ni = 0; ni < 4; ++ni)
        b[ni] = *(const bf16x8*)(Bs + (wn + ni * 16 + l15) * 128 + so);
#pragma unroll
      for (int mi = 0; mi < 4; ++mi)
#pragma unroll
        for (int ni = 0; ni < 4; ++ni)
          acc[mi][ni] = __builtin_amdgcn_mfma_f32_16x16x32_bf16(a[mi], b[ni], acc[mi][ni], 0, 0, 0);
    }
    __syncthreads();
  }

  const int rb = (lane >> 4) * 4;

  if (z != 2) {
#pragma unroll
    for (int mi = 0; mi < 4; ++mi) {
#pragma unroll
      for (int r = 0; r < 4; ++r) {
        const int row = m0 + wm + mi * 16 + rb + r;
        const int bb = row >> 11, s = row & 2047;
#pragma unroll
        for (int ni = 0; ni < 4; ++ni) {
          const int col = n0 + wn + ni * 16 + l15;
          const int hh = col >> 6, d = col & 63;
          C[((size_t)(bb * NH + hh) * SEQ + s) * DK + d] = bf16_rne(acc[mi][ni][r]);
        }
      }
    }
  } else {
    // V: transposed write via LDS (tile covers heads (n0>>6)+{0,1})
    const int bb = m0 >> 11;
    const int s0 = m0 & 2047;
    u16* const T = sh;   // 64 x 136, XOR-swizzled along s
    const int dRd  = tid >> 2;
    const int cbRd = (tid & 3) * 32;
    const int swzR = ((dRd >> 3) & 7) << 3;
#pragma unroll
    for (int p = 0; p < 2; ++p) {
      if ((w & 1) == p) {
#pragma unroll
        for (int mi = 0; mi < 4; ++mi)
#pragma unroll
          for (int r = 0; r < 4; ++r) {
            const int s_local = wm + mi * 16 + rb + r;
#pragma unroll
            for (int ni = 0; ni < 4; ++ni) {
              const int d = ni * 16 + l15;
              T[d * 136 + (s_local ^ (((d >> 3) & 7) << 3))] = bf16_rne(acc[mi][ni][r]);
            }
          }
      }
      __syncthreads();
      u16* dst = C + ((size_t)(bb * NH + (n0 >> 6) + p) * DK + dRd) * SEQ + s0 + cbRd;
#pragma unroll
      for (int k = 0; k < 4; ++k) {
        int4 v = *(const int4*)(T + dRd * 136 + ((cbRd + 8 * k) ^ swzR));
        *(int4*)(dst + 8 * k) = v;
      }
      __syncthreads();
    }
  }
}

// ---------------------------------------------------------------- out GEMM
// (R13: same BK=128 structure as gemm_qkv)
__global__ __launch_bounds__(256) void gemm_out(
    const u16* __restrict__ A, const u16* __restrict__ Wt, float* __restrict__ C)
{
  __shared__ __align__(16) u16 sh[32768];  // As 16384 + Bs 16384 (BK=128)
  u16* const As = sh;
  u16* const Bs = sh + 16384;

  const int tid  = threadIdx.x;
  const int lane = tid & 63;
  const int w    = tid >> 6;
  const int wm   = (w >> 1) * 64;
  const int wn   = (w & 1) * 64;
  const int m0   = blockIdx.x * 128;
  const int n0   = blockIdx.y * 128;

  const int l15  = lane & 15;
  const int g    = lane >> 4;

  const int grow = tid >> 4;
  const int gcol = ((tid & 15) ^ grow) * 8;

  const u16* const gaB = A  + (size_t)(m0 + grow) * 1024 + gcol;
  const u16* const gbB = Wt + (size_t)(n0 + grow) * 1024 + gcol;

  f32x4 acc[4][4] = {};

  for (int k0 = 0; k0 < 1024; k0 += 128) {
#pragma unroll
    for (int i = 0; i < 8; ++i) {
      GLD(gaB + (size_t)i * 16 * 1024 + k0, As + i * 2048 + tid * 8);
      GLD(gbB + (size_t)i * 16 * 1024 + k0, Bs + i * 2048 + tid * 8);
    }
    __syncthreads();
#pragma unroll
    for (int kk = 0; kk < 4; ++kk) {
      const int so = ((kk * 4 + g) ^ l15) * 8;
      bf16x8 a[4], b[4];
#pragma unroll
      for (int mi = 0; mi < 4; ++mi)
        a[mi] = *(const bf16x8*)(As + (wm + mi * 16 + l15) * 128 + so);
#pragma unroll
      for (int ni = 0; ni < 4; ++ni)
        b[ni] = *(const bf16x8*)(Bs + (wn + ni * 16 + l15) * 128 + so);
#pragma unroll
      for (int mi = 0; mi < 4; ++mi)
#pragma unroll
        for (int ni = 0; ni < 4; ++ni)
          acc[mi][ni] = __builtin_amdgcn_mfma_f32_16x16x32_bf16(a[mi], b[ni], acc[mi][ni], 0, 0, 0);
    }
    __syncthreads();
  }

  const int rb = (lane >> 4) * 4;
#pragma unroll
  for (int mi = 0; mi < 4; ++mi) {
#pragma unroll
    for (int r = 0; r < 4; ++r) {
      const int row = m0 + wm + mi * 16 + rb + r;
#pragma unroll
      for (int ni = 0; ni < 4; ++ni) {
        const int col = n0 + wn + ni * 16 + l15;
        C[(size_t)row * 1024 + col] = acc[mi][ni][r];
      }
    }
  }
}

// ---------------------------------------------------------------- attention
// (unchanged from R12: paired 64-key sub-tiles, double-buffered, one barrier
// per pair; no-max base-2 softmax, in-register P, P*ones row-sum on MFMA)
__global__ __launch_bounds__(256) void attn64(
    const u16* __restrict__ Q, const u16* __restrict__ K, const u16* __restrict__ VT,
    u16* __restrict__ O)
{
  const int b   = blockIdx.x;              // 0..511
  const int xcd = b & 7;
  const int bh  = xcd * 8 + ((b >> 3) & 7);
  const int it  = b >> 6;                  // 0..7

  const int tid  = threadIdx.x;
  const int lane = tid & 63;
  const int w    = tid >> 6;

  const u16* Qp = Q  + (size_t)bh * SEQ * DK;
  const u16* Kp = K  + (size_t)bh * SEQ * DK;
  const u16* Vp = VT + (size_t)bh * DK * SEQ;   // [d][s]

  __shared__ __align__(16) u16 Ks[2][2][64 * 64];  // [buf][sub][key][d]
  __shared__ __align__(16) u16 Vs[2][2][64 * 64];  // [buf][sub][d][key]

  const int l15 = lane & 15;
  const int g   = lane >> 4;
  const int g8  = g * 8;

  const int r_  = tid >> 3;                         // 0..31
  const int cS_ = ((tid & 7) ^ (r_ & 7)) * 8;       // u16 col offset in row
  const u16* kgA = Kp + (size_t)r_ * DK + cS_;          // + tau*64*DK
  const u16* kgB = Kp + (size_t)(r_ + 32) * DK + cS_;   // (r_+32)&7 == r_&7
  const u16* vgA = Vp + (size_t)r_ * SEQ + cS_;         // + tau*64
  const u16* vgB = Vp + (size_t)(r_ + 32) * SEQ + cS_;

  const int sS0 = ( g      ^ (l15 & 7)) * 8;
  const int sS1 = ((4 + g) ^ (l15 & 7)) * 8;

  const int b_ = bh >> 4, h_ = bh & 15;

  bf16x8 vone;
#pragma unroll
  for (int i = 0; i < 8; ++i) vone[i] = (short)0x3F80;   // bf16 1.0

  for (int pass = 0; pass < 2; ++pass) {
    const int qt = pass ? 15 - it : it;   // 128-row q-tile index, 0..15
    const int qw = qt * 128 + w * 32;     // wave's 32 rows

    bf16x8 qf[2][2];
#pragma unroll
    for (int j = 0; j < 2; ++j)
#pragma unroll
      for (int kk = 0; kk < 2; ++kk)
        qf[j][kk] = *(const bf16x8*)(Qp + (size_t)(qw + j * 16 + l15) * DK + kk * 32 + g8);

    f32x4 o[2][4] = {};                   // per group: O[16 q][64 d], C-layout
    f32x4 osum[2] = {};                   // row-sums via P*ones (same layout)

    __syncthreads();                      // prev pass's readers done (parity varies)
    // prologue: stage pair 0 (tiles 0,1) -> buf 0
#pragma unroll
    for (int u = 0; u < 2; ++u) {
      const size_t ko = (size_t)u * 64 * DK;
      const int    vo = u * 64;
      GLD(kgA + ko, &Ks[0][u][0] + tid * 8);
      GLD(kgB + ko, &Ks[0][u][2048] + tid * 8);
      GLD(vgA + vo, &Vs[0][u][0] + tid * 8);
      GLD(vgB + vo, &Vs[0][u][2048] + tid * 8);
    }

    for (int p2 = 0; p2 <= qt; ++p2) {
      __syncthreads();                 // pair p2 landed; other buf's readers done
      const int cb = p2 & 1;
      if (p2 < qt) {                   // stage pair p2+1 into the other buffer
        const int nb = cb ^ 1;
#pragma unroll
        for (int u = 0; u < 2; ++u) {
          const int tau = 2 * (p2 + 1) + u;
          const size_t ko = (size_t)tau * 64 * DK;
          const int    vo = tau * 64;
          GLD(kgA + ko, &Ks[nb][u][0] + tid * 8);
          GLD(kgB + ko, &Ks[nb][u][2048] + tid * 8);
          GLD(vgA + vo, &Vs[nb][u][0] + tid * 8);
          GLD(vgB + vo, &Vs[nb][u][2048] + tid * 8);
        }
      }

#pragma unroll
      for (int u = 0; u < 2; ++u) {
        const int tau = 2 * p2 + u;
        if (64 * tau >= qw + 32) continue;   // sub-tile beyond wave's diagonal

        const u16* const ksb = &Ks[cb][u][0];
        const u16* const vsb = &Vs[cb][u][0];

        // ---- S^T = K . Q^T, both row-groups sharing the K frags
        f32x4 st[2][4] = {};
#pragma unroll
        for (int kk = 0; kk < 2; ++kk) {
          const int so = kk ? sS1 : sS0;
#pragma unroll
          for (int mt = 0; mt < 4; ++mt) {
            const bf16x8 kf = *(const bf16x8*)(ksb + (mt * 16 + l15) * 64 + so);
            st[0][mt] = __builtin_amdgcn_mfma_f32_16x16x32_bf16(kf, qf[0][kk], st[0][mt], 0, 0, 0);
            st[1][mt] = __builtin_amdgcn_mfma_f32_16x16x32_bf16(kf, qf[1][kk], st[1][mt], 0, 0, 0);
          }
        }

        bf16x8 pa[2][2];                 // in-register P fragments for PV
#pragma unroll
        for (int j = 0; j < 2; ++j) {
          const int qg = qw + j * 16;
          if (qg <= 64 * tau + 48) {     // diagonal overlap: apply causal mask
            const int qrow = qg + l15;
#pragma unroll
            for (int mt = 0; mt < 4; ++mt)
#pragma unroll
              for (int r = 0; r < 4; ++r)
                if (64 * tau + mt * 16 + g * 4 + r > qrow) st[j][mt][r] = -1e30f;
          }

          // ---- P = 2^S (no max subtraction needed in f32 base-2)
          unsigned pkx[4], pky[4];
#pragma unroll
          for (int mt = 0; mt < 4; ++mt) {
            float p0 = exp2_raw(st[j][mt][0]);
            float p1 = exp2_raw(st[j][mt][1]);
            float p2_ = exp2_raw(st[j][mt][2]);
            float p3 = exp2_raw(st[j][mt][3]);
            pkx[mt] = cvt_pk_bf16(p0, p1);
            pky[mt] = cvt_pk_bf16(p2_, p3);
          }
          pa[j][0] = pfrag(pkx[0], pky[0], pkx[1], pky[1]);
          pa[j][1] = pfrag(pkx[2], pky[2], pkx[3], pky[3]);
        }

        // ---- O += P . V ; osum += P . ones  (all fragments in registers)
#pragma unroll
        for (int kk = 0; kk < 2; ++kk) {
          const int so = kk ? sS1 : sS0;
          osum[0] = __builtin_amdgcn_mfma_f32_16x16x32_bf16(pa[0][kk], vone, osum[0], 0, 0, 0);
          osum[1] = __builtin_amdgcn_mfma_f32_16x16x32_bf16(pa[1][kk], vone, osum[1], 0, 0, 0);
#pragma unroll
          for (int nt = 0; nt < 4; ++nt) {
            const bf16x8 vv = *(const bf16x8*)(vsb + (nt * 16 + l15) * 64 + so);
            o[0][nt] = __builtin_amdgcn_mfma_f32_16x16x32_bf16(pa[0][kk], vv, o[0][nt], 0, 0, 0);
            o[1][nt] = __builtin_amdgcn_mfma_f32_16x16x32_bf16(pa[1][kk], vv, o[1][nt], 0, 0, 0);
          }
        }
      }
    }

    // epilogue: O[q][d] / l  -> Ob[b][s][h*64+d]
    // osum[j][r] is the denominator for row g*4+r in THIS lane (no shuffle).
#pragma unroll
    for (int j = 0; j < 2; ++j) {
#pragma unroll
      for (int r = 0; r < 4; ++r) {
        const float inv = 1.0f / osum[j][r];
        const int   s   = qw + j * 16 + g * 4 + r;
#pragma unroll
        for (int nt = 0; nt < 4; ++nt) {
          const int d = nt * 16 + l15;
          O[((size_t)b_ * SEQ + s) * EMB + h_ * DK + d] = bf16_rne(o[j][nt][r] * inv);
        }
      }
    }
  }
}

// ---------------------------------------------------------------- launch
extern "C" void kernel_launch(void* const* d_in, const int* in_sizes, int n_in,
                              void* d_out, int out_size, void* d_ws, size_t ws_size,
                              hipStream_t stream) {
  (void)in_sizes; (void)n_in;
  const float* x  = (const float*)d_in[0];
  const float* WQ = (const float*)d_in[1];
  const float* WK = (const float*)d_in[2];
  const float* WV = (const float*)d_in[3];
  const float* WO = (const float*)d_in[4];
  float* out = (float*)d_out;

  const size_t MTOK = (size_t)4 * SEQ;        // 8192 rows
  const size_t NTOK = MTOK * EMB;             // 8,388,608 elements
  const size_t NW   = (size_t)EMB * EMB;      // 1,048,576 elements

  const size_t NEEDED = 4 * NTOK * sizeof(u16);   // 64 MiB: Q,K,VT,Ob (bf16)
  if (ws_size < NEEDED) {
    fill_sig<<<dim3((out_size + 255) / 256), 256, 0, stream>>>(out, out_size);
    return;
  }

  u16* ws  = (u16*)d_ws;
  u16* Qb  = ws;
  u16* Kb  = Qb + NTOK;
  u16* VTb = Kb + NTOK;
  u16* Ob  = VTb + NTOK;
  // scratch in dead regions:
  u16* xb  = (u16*)d_out;   // d_out (32MB f32) unused until gemm_out; xb = 16MB
  u16* WQt = Ob;            // Ob not written until attn64
  u16* WKt = WQt + NW;
  u16* WVt = WKt + NW;
  u16* WOt = Qb;            // Qb dead after attn64

  cvt_x<<<dim3(4096), 256, 0, stream>>>(x, xb);
  tcvt3<<<dim3(16, 16, 3), 256, 0, stream>>>(WQ, WK, WV, WQt, WKt, WVt);
  gemm_qkv<<<dim3(MTOK / 128, EMB / 128, 3), 256, 0, stream>>>(
      xb, WQt, WKt, WVt, Qb, Kb, VTb);
  attn64<<<dim3(512), 256, 0, stream>>>(Qb, Kb, VTb, Ob);
  tcvt1<<<dim3(16, 16), 256, 0, stream>>>(WO, WOt);
  gemm_out<<<dim3(MTOK / 128, EMB / 128), 256, 0, stream>>>(Ob, WOt, out);
}

// Round 14
// 241.848 us; speedup vs baseline: 1.1140x; 1.1140x over previous
//
#include <hip/hip_runtime.h>

typedef unsigned short u16;
typedef short bf16x8 __attribute__((ext_vector_type(8)));
typedef float f32x4 __attribute__((ext_vector_type(4)));

// B=4, S=2048, E=1024, H=16, dk=64
#define SEQ   2048
#define EMB   1024
#define NH    16
#define DK    64

// softmax in base-2: Q path pre-scaled by 0.125 * log2(e)  (baked into WQt)
#define QSCALE 0.1803368801111144f

__device__ __forceinline__ u16 bf16_rne(float f) {
  union { float f; unsigned u; } x;
  x.f = f;
  unsigned u = x.u;
  u += 0x7fffu + ((u >> 16) & 1u);
  return (u16)(u >> 16);
}

// packed f32x2 -> bf16x2 (lo = a, hi = b), 1 VALU op
__device__ __forceinline__ unsigned cvt_pk_bf16(float a, float b) {
  unsigned r;
  asm("v_cvt_pk_bf16_f32 %0, %1, %2" : "=v"(r) : "v"(a), "v"(b));
  return r;
}

// raw v_exp_f32: D = 2^S0 (single instruction; libm exp2f adds range fixup)
__device__ __forceinline__ float exp2_raw(float x) {
#if __has_builtin(__builtin_amdgcn_exp2f)
  return __builtin_amdgcn_exp2f(x);
#else
  float r; asm("v_exp_f32 %0, %1" : "=v"(r) : "v"(x)); return r;
#endif
}

// Redistribute packed P words into the PV A-fragment, all on the VALU pipe.
__device__ __forceinline__ bf16x8 pfrag(unsigned x0, unsigned y0,
                                        unsigned x1, unsigned y1) {
  asm("v_permlane32_swap_b32 %0, %1" : "+v"(x0), "+v"(x1));
  asm("v_permlane32_swap_b32 %0, %1" : "+v"(y0), "+v"(y1));
  asm("v_permlane16_swap_b32 %0, %1" : "+v"(x0), "+v"(x1));
  asm("v_permlane16_swap_b32 %0, %1" : "+v"(y0), "+v"(y1));
  union { unsigned u[4]; bf16x8 v; } f;
  f.u[0] = x0; f.u[1] = y0; f.u[2] = x1; f.u[3] = y1;
  return f.v;
}

#define GLD(src, dst)                                                         \
  __builtin_amdgcn_global_load_lds(                                           \
      (const __attribute__((address_space(1))) void*)(src),                   \
      (__attribute__((address_space(3))) void*)(dst), 16, 0, 0)

// ---------------------------------------------------------------- fallback
__global__ __launch_bounds__(256) void fill_sig(float* __restrict__ out, int n) {
  const int i = blockIdx.x * 256 + threadIdx.x;
  if (i < n) out[i] = 1.0f;   // "workspace too small" signal
}

// ---------------------------------------------------------------- prep
// Merged cvt_x (blocks 0..4095) + tcvt3 (blocks 4096..4863): one dispatch,
// tcvt3's 768 blocks fill CUs during cvt_x's tail. Bodies are the verified
// R12 kernels unchanged; each block takes exactly one branch (uniform).
__global__ __launch_bounds__(256) void prep(
    const float* __restrict__ x, u16* __restrict__ xb,
    const float* __restrict__ s0, const float* __restrict__ s1,
    const float* __restrict__ s2,
    u16* __restrict__ d0, u16* __restrict__ d1, u16* __restrict__ d2)
{
  const int b = blockIdx.x;
  if (b < 4096) {                       // ---- cvt_x body
    const size_t i = ((size_t)b * 256 + threadIdx.x) * 8;
    float4 v0 = *(const float4*)(x + i);
    float4 v1 = *(const float4*)(x + i + 4);
    union { int4 v; u16 h[8]; } c;
    c.h[0] = bf16_rne(v0.x); c.h[1] = bf16_rne(v0.y);
    c.h[2] = bf16_rne(v0.z); c.h[3] = bf16_rne(v0.w);
    c.h[4] = bf16_rne(v1.x); c.h[5] = bf16_rne(v1.y);
    c.h[6] = bf16_rne(v1.z); c.h[7] = bf16_rne(v1.w);
    *(int4*)(xb + i) = c.v;
    return;
  }
  // ---- tcvt3 body
  __shared__ u16 tile[64][65];
  const int idx = b - 4096;             // 0..767
  const int z   = idx >> 8;             // 0..2
  const int rem = idx & 255;
  const float* src = (z == 0) ? s0 : (z == 1) ? s1 : s2;
  u16* dst = (z == 0) ? d0 : (z == 1) ? d1 : d2;
  const float sc = (z == 0) ? QSCALE : 1.0f;
  const int bx = (rem & 15) * 64, by = (rem >> 4) * 64;
  for (int i = threadIdx.x; i < 64 * 64; i += 256) {
    const int r = i >> 6, c = i & 63;
    tile[c][r] = bf16_rne(src[(size_t)(by + r) * EMB + bx + c] * sc);
  }
  __syncthreads();
  for (int i = threadIdx.x; i < 64 * 64; i += 256) {
    const int r = i >> 6, c = i & 63;
    dst[(size_t)(bx + r) * EMB + by + c] = tile[r][c];
  }
}

__global__ __launch_bounds__(256) void tcvt1(const float* __restrict__ src,
                                             u16* __restrict__ dst) {
  __shared__ u16 tile[64][65];
  const int bx = blockIdx.x * 64, by = blockIdx.y * 64;
  for (int i = threadIdx.x; i < 64 * 64; i += 256) {
    const int r = i >> 6, c = i & 63;
    tile[c][r] = bf16_rne(src[(size_t)(by + r) * EMB + bx + c]);
  }
  __syncthreads();
  for (int i = threadIdx.x; i < 64 * 64; i += 256) {
    const int r = i >> 6, c = i & 63;
    dst[(size_t)(bx + r) * EMB + by + c] = tile[r][c];
  }
}

// ---------------------------------------------------------------- QKV GEMM
// (exact R12: BK=64 single-buffer 2-barrier, 8-slot XOR swizzle — best verified)
__global__ __launch_bounds__(256) void gemm_qkv(
    const u16* __restrict__ A,
    const u16* __restrict__ T0, const u16* __restrict__ T1, const u16* __restrict__ T2,
    u16* __restrict__ C0, u16* __restrict__ C1, u16* __restrict__ C2)
{
  const int z = blockIdx.z;
  const u16* Wt = (z == 0) ? T0 : (z == 1) ? T1 : T2;
  u16* C = (z == 0) ? C0 : (z == 1) ? C1 : C2;

  __shared__ __align__(16) u16 sh[16384];  // As 8192 + Bs 8192 (BK=64); T reuse
  u16* const As = sh;
  u16* const Bs = sh + 8192;

  const int tid  = threadIdx.x;
  const int lane = tid & 63;
  const int w    = tid >> 6;
  const int wm   = (w >> 1) * 64;
  const int wn   = (w & 1) * 64;
  const int m0   = blockIdx.x * 128;
  const int n0   = blockIdx.y * 128;

  const int l15  = lane & 15;
  const int g    = lane >> 4;
  const int sw   = l15 & 7;                 // read-slot XOR key (row & 7)

  const int lrow = lane >> 3;               // 0..7: row within 8-row GLD chunk
  const int lcol = ((lane & 7) ^ lrow) * 8; // pre-swizzled source col (u16)

  const int r0 = w * 32;                    // wave stages rows [r0, r0+32)
  const u16* const gaB = A  + (size_t)(m0 + lrow) * 1024 + lcol;
  const u16* const gbB = Wt + (size_t)(n0 + lrow) * 1024 + lcol;

  f32x4 acc[4][4] = {};

  for (int k0 = 0; k0 < 1024; k0 += 64) {
#pragma unroll
    for (int i = 0; i < 4; ++i) {
      const int r = r0 + i * 8;
      GLD(gaB + (size_t)r * 1024 + k0, As + r * 64);
      GLD(gbB + (size_t)r * 1024 + k0, Bs + r * 64);
    }
    __syncthreads();
#pragma unroll
    for (int kk = 0; kk < 2; ++kk) {
      bf16x8 a[4], b[4];
#pragma unroll
      for (int mi = 0; mi < 4; ++mi)
        a[mi] = *(const bf16x8*)(As + (wm + mi * 16 + l15) * 64 + ((kk * 4 + g) ^ sw) * 8);
#pragma unroll
      for (int ni = 0; ni < 4; ++ni)
        b[ni] = *(const bf16x8*)(Bs + (wn + ni * 16 + l15) * 64 + ((kk * 4 + g) ^ sw) * 8);
#pragma unroll
      for (int mi = 0; mi < 4; ++mi)
#pragma unroll
        for (int ni = 0; ni < 4; ++ni)
          acc[mi][ni] = __builtin_amdgcn_mfma_f32_16x16x32_bf16(a[mi], b[ni], acc[mi][ni], 0, 0, 0);
    }
    __syncthreads();
  }

  const int rb = (lane >> 4) * 4;

  if (z != 2) {
#pragma unroll
    for (int mi = 0; mi < 4; ++mi) {
#pragma unroll
      for (int r = 0; r < 4; ++r) {
        const int row = m0 + wm + mi * 16 + rb + r;
        const int bb = row >> 11, s = row & 2047;
#pragma unroll
        for (int ni = 0; ni < 4; ++ni) {
          const int col = n0 + wn + ni * 16 + l15;
          const int hh = col >> 6, d = col & 63;
          C[((size_t)(bb * NH + hh) * SEQ + s) * DK + d] = bf16_rne(acc[mi][ni][r]);
        }
      }
    }
  } else {
    // V: transposed write via LDS (tile covers heads (n0>>6)+{0,1})
    const int bb = m0 >> 11;
    const int s0 = m0 & 2047;
    u16* const T = sh;   // 64 x 136, XOR-swizzled along s
    const int dRd  = tid >> 2;
    const int cbRd = (tid & 3) * 32;
    const int swzR = ((dRd >> 3) & 7) << 3;
#pragma unroll
    for (int p = 0; p < 2; ++p) {
      if ((w & 1) == p) {
#pragma unroll
        for (int mi = 0; mi < 4; ++mi)
#pragma unroll
          for (int r = 0; r < 4; ++r) {
            const int s_local = wm + mi * 16 + rb + r;
#pragma unroll
            for (int ni = 0; ni < 4; ++ni) {
              const int d = ni * 16 + l15;
              T[d * 136 + (s_local ^ (((d >> 3) & 7) << 3))] = bf16_rne(acc[mi][ni][r]);
            }
          }
      }
      __syncthreads();
      u16* dst = C + ((size_t)(bb * NH + (n0 >> 6) + p) * DK + dRd) * SEQ + s0 + cbRd;
#pragma unroll
      for (int k = 0; k < 4; ++k) {
        int4 v = *(const int4*)(T + dRd * 136 + ((cbRd + 8 * k) ^ swzR));
        *(int4*)(dst + 8 * k) = v;
      }
      __syncthreads();
    }
  }
}

// ---------------------------------------------------------------- out GEMM
// (exact R12: BK=64)
__global__ __launch_bounds__(256) void gemm_out(
    const u16* __restrict__ A, const u16* __restrict__ Wt, float* __restrict__ C)
{
  __shared__ __align__(16) u16 sh[16384];  // As 8192 + Bs 8192 (BK=64)
  u16* const As = sh;
  u16* const Bs = sh + 8192;

  const int tid  = threadIdx.x;
  const int lane = tid & 63;
  const int w    = tid >> 6;
  const int wm   = (w >> 1) * 64;
  const int wn   = (w & 1) * 64;
  const int m0   = blockIdx.x * 128;
  const int n0   = blockIdx.y * 128;

  const int l15  = lane & 15;
  const int g    = lane >> 4;
  const int sw   = l15 & 7;

  const int lrow = lane >> 3;
  const int lcol = ((lane & 7) ^ lrow) * 8;

  const int r0 = w * 32;
  const u16* const gaB = A  + (size_t)(m0 + lrow) * 1024 + lcol;
  const u16* const gbB = Wt + (size_t)(n0 + lrow) * 1024 + lcol;

  f32x4 acc[4][4] = {};

  for (int k0 = 0; k0 < 1024; k0 += 64) {
#pragma unroll
    for (int i = 0; i < 4; ++i) {
      const int r = r0 + i * 8;
      GLD(gaB + (size_t)r * 1024 + k0, As + r * 64);
      GLD(gbB + (size_t)r * 1024 + k0, Bs + r * 64);
    }
    __syncthreads();
#pragma unroll
    for (int kk = 0; kk < 2; ++kk) {
      bf16x8 a[4], b[4];
#pragma unroll
      for (int mi = 0; mi < 4; ++mi)
        a[mi] = *(const bf16x8*)(As + (wm + mi * 16 + l15) * 64 + ((kk * 4 + g) ^ sw) * 8);
#pragma unroll
      for (int ni = 0; ni < 4; ++ni)
        b[ni] = *(const bf16x8*)(Bs + (wn + ni * 16 + l15) * 64 + ((kk * 4 + g) ^ sw) * 8);
#pragma unroll
      for (int mi = 0; mi < 4; ++mi)
#pragma unroll
        for (int ni = 0; ni < 4; ++ni)
          acc[mi][ni] = __builtin_amdgcn_mfma_f32_16x16x32_bf16(a[mi], b[ni], acc[mi][ni], 0, 0, 0);
    }
    __syncthreads();
  }

  const int rb = (lane >> 4) * 4;
#pragma unroll
  for (int mi = 0; mi < 4; ++mi) {
#pragma unroll
    for (int r = 0; r < 4; ++r) {
      const int row = m0 + wm + mi * 16 + rb + r;
#pragma unroll
      for (int ni = 0; ni < 4; ++ni) {
        const int col = n0 + wn + ni * 16 + l15;
        C[(size_t)row * 1024 + col] = acc[mi][ni][r];
      }
    }
  }
}

// ---------------------------------------------------------------- attention
// (exact R12: paired 64-key sub-tiles, double-buffered, one barrier per pair;
// no-max base-2 softmax, in-register P, P*ones row-sum on MFMA)
__global__ __launch_bounds__(256) void attn64(
    const u16* __restrict__ Q, const u16* __restrict__ K, const u16* __restrict__ VT,
    u16* __restrict__ O)
{
  const int b   = blockIdx.x;              // 0..511
  const int xcd = b & 7;
  const int bh  = xcd * 8 + ((b >> 3) & 7);
  const int it  = b >> 6;                  // 0..7

  const int tid  = threadIdx.x;
  const int lane = tid & 63;
  const int w    = tid >> 6;

  const u16* Qp = Q  + (size_t)bh * SEQ * DK;
  const u16* Kp = K  + (size_t)bh * SEQ * DK;
  const u16* Vp = VT + (size_t)bh * DK * SEQ;   // [d][s]

  __shared__ __align__(16) u16 Ks[2][2][64 * 64];  // [buf][sub][key][d]
  __shared__ __align__(16) u16 Vs[2][2][64 * 64];  // [buf][sub][d][key]

  const int l15 = lane & 15;
  const int g   = lane >> 4;
  const int g8  = g * 8;

  const int r_  = tid >> 3;                         // 0..31
  const int cS_ = ((tid & 7) ^ (r_ & 7)) * 8;       // u16 col offset in row
  const u16* kgA = Kp + (size_t)r_ * DK + cS_;          // + tau*64*DK
  const u16* kgB = Kp + (size_t)(r_ + 32) * DK + cS_;   // (r_+32)&7 == r_&7
  const u16* vgA = Vp + (size_t)r_ * SEQ + cS_;         // + tau*64
  const u16* vgB = Vp + (size_t)(r_ + 32) * SEQ + cS_;

  const int sS0 = ( g      ^ (l15 & 7)) * 8;
  const int sS1 = ((4 + g) ^ (l15 & 7)) * 8;

  const int b_ = bh >> 4, h_ = bh & 15;

  bf16x8 vone;
#pragma unroll
  for (int i = 0; i < 8; ++i) vone[i] = (short)0x3F80;   // bf16 1.0

  for (int pass = 0; pass < 2; ++pass) {
    const int qt = pass ? 15 - it : it;   // 128-row q-tile index, 0..15
    const int qw = qt * 128 + w * 32;     // wave's 32 rows

    bf16x8 qf[2][2];
#pragma unroll
    for (int j = 0; j < 2; ++j)
#pragma unroll
      for (int kk = 0; kk < 2; ++kk)
        qf[j][kk] = *(const bf16x8*)(Qp + (size_t)(qw + j * 16 + l15) * DK + kk * 32 + g8);

    f32x4 o[2][4] = {};                   // per group: O[16 q][64 d], C-layout
    f32x4 osum[2] = {};                   // row-sums via P*ones (same layout)

    __syncthreads();                      // prev pass's readers done (parity varies)
    // prologue: stage pair 0 (tiles 0,1) -> buf 0
#pragma unroll
    for (int u = 0; u < 2; ++u) {
      const size_t ko = (size_t)u * 64 * DK;
      const int    vo = u * 64;
      GLD(kgA + ko, &Ks[0][u][0] + tid * 8);
      GLD(kgB + ko, &Ks[0][u][2048] + tid * 8);
      GLD(vgA + vo, &Vs[0][u][0] + tid * 8);
      GLD(vgB + vo, &Vs[0][u][2048] + tid * 8);
    }

    for (int p2 = 0; p2 <= qt; ++p2) {
      __syncthreads();                 // pair p2 landed; other buf's readers done
      const int cb = p2 & 1;
      if (p2 < qt) {                   // stage pair p2+1 into the other buffer
        const int nb = cb ^ 1;
#pragma unroll
        for (int u = 0; u < 2; ++u) {
          const int tau = 2 * (p2 + 1) + u;
          const size_t ko = (size_t)tau * 64 * DK;
          const int    vo = tau * 64;
          GLD(kgA + ko, &Ks[nb][u][0] + tid * 8);
          GLD(kgB + ko, &Ks[nb][u][2048] + tid * 8);
          GLD(vgA + vo, &Vs[nb][u][0] + tid * 8);
          GLD(vgB + vo, &Vs[nb][u][2048] + tid * 8);
        }
      }

#pragma unroll
      for (int u = 0; u < 2; ++u) {
        const int tau = 2 * p2 + u;
        if (64 * tau >= qw + 32) continue;   // sub-tile beyond wave's diagonal

        const u16* const ksb = &Ks[cb][u][0];
        const u16* const vsb = &Vs[cb][u][0];

        // ---- S^T = K . Q^T, both row-groups sharing the K frags
        f32x4 st[2][4] = {};
#pragma unroll
        for (int kk = 0; kk < 2; ++kk) {
          const int so = kk ? sS1 : sS0;
#pragma unroll
          for (int mt = 0; mt < 4; ++mt) {
            const bf16x8 kf = *(const bf16x8*)(ksb + (mt * 16 + l15) * 64 + so);
            st[0][mt] = __builtin_amdgcn_mfma_f32_16x16x32_bf16(kf, qf[0][kk], st[0][mt], 0, 0, 0);
            st[1][mt] = __builtin_amdgcn_mfma_f32_16x16x32_bf16(kf, qf[1][kk], st[1][mt], 0, 0, 0);
          }
        }

        bf16x8 pa[2][2];                 // in-register P fragments for PV
#pragma unroll
        for (int j = 0; j < 2; ++j) {
          const int qg = qw + j * 16;
          if (qg <= 64 * tau + 48) {     // diagonal overlap: apply causal mask
            const int qrow = qg + l15;
#pragma unroll
            for (int mt = 0; mt < 4; ++mt)
#pragma unroll
              for (int r = 0; r < 4; ++r)
                if (64 * tau + mt * 16 + g * 4 + r > qrow) st[j][mt][r] = -1e30f;
          }

          // ---- P = 2^S (no max subtraction needed in f32 base-2)
          unsigned pkx[4], pky[4];
#pragma unroll
          for (int mt = 0; mt < 4; ++mt) {
            float p0 = exp2_raw(st[j][mt][0]);
            float p1 = exp2_raw(st[j][mt][1]);
            float p2_ = exp2_raw(st[j][mt][2]);
            float p3 = exp2_raw(st[j][mt][3]);
            pkx[mt] = cvt_pk_bf16(p0, p1);
            pky[mt] = cvt_pk_bf16(p2_, p3);
          }
          pa[j][0] = pfrag(pkx[0], pky[0], pkx[1], pky[1]);
          pa[j][1] = pfrag(pkx[2], pky[2], pkx[3], pky[3]);
        }

        // ---- O += P . V ; osum += P . ones  (all fragments in registers)
#pragma unroll
        for (int kk = 0; kk < 2; ++kk) {
          const int so = kk ? sS1 : sS0;
          osum[0] = __builtin_amdgcn_mfma_f32_16x16x32_bf16(pa[0][kk], vone, osum[0], 0, 0, 0);
          osum[1] = __builtin_amdgcn_mfma_f32_16x16x32_bf16(pa[1][kk], vone, osum[1], 0, 0, 0);
#pragma unroll
          for (int nt = 0; nt < 4; ++nt) {
            const bf16x8 vv = *(const bf16x8*)(vsb + (nt * 16 + l15) * 64 + so);
            o[0][nt] = __builtin_amdgcn_mfma_f32_16x16x32_bf16(pa[0][kk], vv, o[0][nt], 0, 0, 0);
            o[1][nt] = __builtin_amdgcn_mfma_f32_16x16x32_bf16(pa[1][kk], vv, o[1][nt], 0, 0, 0);
          }
        }
      }
    }

    // epilogue: O[q][d] / l  -> Ob[b][s][h*64+d]
    // osum[j][r] is the denominator for row g*4+r in THIS lane (no shuffle).
#pragma unroll
    for (int j = 0; j < 2; ++j) {
#pragma unroll
      for (int r = 0; r < 4; ++r) {
        const float inv = 1.0f / osum[j][r];
        const int   s   = qw + j * 16 + g * 4 + r;
#pragma unroll
        for (int nt = 0; nt < 4; ++nt) {
          const int d = nt * 16 + l15;
          O[((size_t)b_ * SEQ + s) * EMB + h_ * DK + d] = bf16_rne(o[j][nt][r] * inv);
        }
      }
    }
  }
}

// ---------------------------------------------------------------- launch
extern "C" void kernel_launch(void* const* d_in, const int* in_sizes, int n_in,
                              void* d_out, int out_size, void* d_ws, size_t ws_size,
                              hipStream_t stream) {
  (void)in_sizes; (void)n_in;
  const float* x  = (const float*)d_in[0];
  const float* WQ = (const float*)d_in[1];
  const float* WK = (const float*)d_in[2];
  const float* WV = (const float*)d_in[3];
  const float* WO = (const float*)d_in[4];
  float* out = (float*)d_out;

  const size_t MTOK = (size_t)4 * SEQ;        // 8192 rows
  const size_t NTOK = MTOK * EMB;             // 8,388,608 elements
  const size_t NW   = (size_t)EMB * EMB;      // 1,048,576 elements

  const size_t NEEDED = 4 * NTOK * sizeof(u16);   // 64 MiB: Q,K,VT,Ob (bf16)
  if (ws_size < NEEDED) {
    fill_sig<<<dim3((out_size + 255) / 256), 256, 0, stream>>>(out, out_size);
    return;
  }

  u16* ws  = (u16*)d_ws;
  u16* Qb  = ws;
  u16* Kb  = Qb + NTOK;
  u16* VTb = Kb + NTOK;
  u16* Ob  = VTb + NTOK;
  // scratch in dead regions:
  u16* xb  = (u16*)d_out;   // d_out (32MB f32) unused until gemm_out; xb = 16MB
  u16* WQt = Ob;            // Ob not written until attn64
  u16* WKt = WQt + NW;
  u16* WVt = WKt + NW;
  u16* WOt = Qb;            // Qb dead after attn64

  prep<<<dim3(4096 + 768), 256, 0, stream>>>(x, xb, WQ, WK, WV, WQt, WKt, WVt);
  gemm_qkv<<<dim3(MTOK / 128, EMB / 128, 3), 256, 0, stream>>>(
      xb, WQt, WKt, WVt, Qb, Kb, VTb);
  attn64<<<dim3(512), 256, 0, stream>>>(Qb, Kb, VTb, Ob);
  tcvt1<<<dim3(16, 16), 256, 0, stream>>>(WO, WOt);
  gemm_out<<<dim3(MTOK / 128, EMB / 128), 256, 0, stream>>>(Ob, WOt, out);
}

// Round 15
// 238.191 us; speedup vs baseline: 1.1312x; 1.0154x over previous
//
#include <hip/hip_runtime.h>

typedef unsigned short u16;
typedef short bf16x8 __attribute__((ext_vector_type(8)));
typedef float f32x4 __attribute__((ext_vector_type(4)));

// B=4, S=2048, E=1024, H=16, dk=64
#define SEQ   2048
#define EMB   1024
#define NH    16
#define DK    64

// softmax in base-2: Q path pre-scaled by 0.125 * log2(e)  (baked into WQt)
#define QSCALE 0.1803368801111144f

__device__ __forceinline__ u16 bf16_rne(float f) {
  union { float f; unsigned u; } x;
  x.f = f;
  unsigned u = x.u;
  u += 0x7fffu + ((u >> 16) & 1u);
  return (u16)(u >> 16);
}

// packed f32x2 -> bf16x2 (lo = a, hi = b), 1 VALU op
__device__ __forceinline__ unsigned cvt_pk_bf16(float a, float b) {
  unsigned r;
  asm("v_cvt_pk_bf16_f32 %0, %1, %2" : "=v"(r) : "v"(a), "v"(b));
  return r;
}

// raw v_exp_f32: D = 2^S0 (single instruction; libm exp2f adds range fixup)
__device__ __forceinline__ float exp2_raw(float x) {
#if __has_builtin(__builtin_amdgcn_exp2f)
  return __builtin_amdgcn_exp2f(x);
#else
  float r; asm("v_exp_f32 %0, %1" : "=v"(r) : "v"(x)); return r;
#endif
}

// Redistribute packed P words into the PV A-fragment, all on the VALU pipe.
__device__ __forceinline__ bf16x8 pfrag(unsigned x0, unsigned y0,
                                        unsigned x1, unsigned y1) {
  asm("v_permlane32_swap_b32 %0, %1" : "+v"(x0), "+v"(x1));
  asm("v_permlane32_swap_b32 %0, %1" : "+v"(y0), "+v"(y1));
  asm("v_permlane16_swap_b32 %0, %1" : "+v"(x0), "+v"(x1));
  asm("v_permlane16_swap_b32 %0, %1" : "+v"(y0), "+v"(y1));
  union { unsigned u[4]; bf16x8 v; } f;
  f.u[0] = x0; f.u[1] = y0; f.u[2] = x1; f.u[3] = y1;
  return f.v;
}

#define GLD(src, dst)                                                         \
  __builtin_amdgcn_global_load_lds(                                           \
      (const __attribute__((address_space(1))) void*)(src),                   \
      (__attribute__((address_space(3))) void*)(dst), 16, 0, 0)

// ---------------------------------------------------------------- fallback
__global__ __launch_bounds__(256) void fill_sig(float* __restrict__ out, int n) {
  const int i = blockIdx.x * 256 + threadIdx.x;
  if (i < n) out[i] = 1.0f;   // "workspace too small" signal
}

// ---------------------------------------------------------------- prep
// Merged cvt_x (blocks 0..4095) + tcvt3 (4096..4863) + optionally tcvt1
// (4864..5119, only when launched with 5120 blocks: WOt in spare ws region).
// Bodies are the verified kernels unchanged; each block takes one branch.
__global__ __launch_bounds__(256) void prep(
    const float* __restrict__ x, u16* __restrict__ xb,
    const float* __restrict__ s0, const float* __restrict__ s1,
    const float* __restrict__ s2,
    u16* __restrict__ d0, u16* __restrict__ d1, u16* __restrict__ d2,
    const float* __restrict__ wo, u16* __restrict__ wot)
{
  const int b = blockIdx.x;
  if (b < 4096) {                       // ---- cvt_x body
    const size_t i = ((size_t)b * 256 + threadIdx.x) * 8;
    float4 v0 = *(const float4*)(x + i);
    float4 v1 = *(const float4*)(x + i + 4);
    union { int4 v; u16 h[8]; } c;
    c.h[0] = bf16_rne(v0.x); c.h[1] = bf16_rne(v0.y);
    c.h[2] = bf16_rne(v0.z); c.h[3] = bf16_rne(v0.w);
    c.h[4] = bf16_rne(v1.x); c.h[5] = bf16_rne(v1.y);
    c.h[6] = bf16_rne(v1.z); c.h[7] = bf16_rne(v1.w);
    *(int4*)(xb + i) = c.v;
    return;
  }
  __shared__ u16 tile[64][65];
  if (b < 4864) {                       // ---- tcvt3 body
    const int idx = b - 4096;           // 0..767
    const int z   = idx >> 8;           // 0..2
    const int rem = idx & 255;
    const float* src = (z == 0) ? s0 : (z == 1) ? s1 : s2;
    u16* dst = (z == 0) ? d0 : (z == 1) ? d1 : d2;
    const float sc = (z == 0) ? QSCALE : 1.0f;
    const int bx = (rem & 15) * 64, by = (rem >> 4) * 64;
    for (int i = threadIdx.x; i < 64 * 64; i += 256) {
      const int r = i >> 6, c = i & 63;
      tile[c][r] = bf16_rne(src[(size_t)(by + r) * EMB + bx + c] * sc);
    }
    __syncthreads();
    for (int i = threadIdx.x; i < 64 * 64; i += 256) {
      const int r = i >> 6, c = i & 63;
      dst[(size_t)(bx + r) * EMB + by + c] = tile[r][c];
    }
    return;
  }
  // ---- tcvt1 body (extended-workspace path only)
  const int idx2 = b - 4864;            // 0..255
  const int bx = (idx2 & 15) * 64, by = (idx2 >> 4) * 64;
  for (int i = threadIdx.x; i < 64 * 64; i += 256) {
    const int r = i >> 6, c = i & 63;
    tile[c][r] = bf16_rne(wo[(size_t)(by + r) * EMB + bx + c]);
  }
  __syncthreads();
  for (int i = threadIdx.x; i < 64 * 64; i += 256) {
    const int r = i >> 6, c = i & 63;
    wot[(size_t)(bx + r) * EMB + by + c] = tile[r][c];
  }
}

__global__ __launch_bounds__(256) void tcvt1(const float* __restrict__ src,
                                             u16* __restrict__ dst) {
  __shared__ u16 tile[64][65];
  const int bx = blockIdx.x * 64, by = blockIdx.y * 64;
  for (int i = threadIdx.x; i < 64 * 64; i += 256) {
    const int r = i >> 6, c = i & 63;
    tile[c][r] = bf16_rne(src[(size_t)(by + r) * EMB + bx + c]);
  }
  __syncthreads();
  for (int i = threadIdx.x; i < 64 * 64; i += 256) {
    const int r = i >> 6, c = i & 63;
    dst[(size_t)(bx + r) * EMB + by + c] = tile[r][c];
  }
}

// ---------------------------------------------------------------- QKV GEMM
// (exact R12: BK=64 single-buffer 2-barrier, 8-slot XOR swizzle — best verified)
__global__ __launch_bounds__(256) void gemm_qkv(
    const u16* __restrict__ A,
    const u16* __restrict__ T0, const u16* __restrict__ T1, const u16* __restrict__ T2,
    u16* __restrict__ C0, u16* __restrict__ C1, u16* __restrict__ C2)
{
  const int z = blockIdx.z;
  const u16* Wt = (z == 0) ? T0 : (z == 1) ? T1 : T2;
  u16* C = (z == 0) ? C0 : (z == 1) ? C1 : C2;

  __shared__ __align__(16) u16 sh[16384];  // As 8192 + Bs 8192 (BK=64); T reuse
  u16* const As = sh;
  u16* const Bs = sh + 8192;

  const int tid  = threadIdx.x;
  const int lane = tid & 63;
  const int w    = tid >> 6;
  const int wm   = (w >> 1) * 64;
  const int wn   = (w & 1) * 64;
  const int m0   = blockIdx.x * 128;
  const int n0   = blockIdx.y * 128;

  const int l15  = lane & 15;
  const int g    = lane >> 4;
  const int sw   = l15 & 7;                 // read-slot XOR key (row & 7)

  const int lrow = lane >> 3;               // 0..7: row within 8-row GLD chunk
  const int lcol = ((lane & 7) ^ lrow) * 8; // pre-swizzled source col (u16)

  const int r0 = w * 32;                    // wave stages rows [r0, r0+32)
  const u16* const gaB = A  + (size_t)(m0 + lrow) * 1024 + lcol;
  const u16* const gbB = Wt + (size_t)(n0 + lrow) * 1024 + lcol;

  f32x4 acc[4][4] = {};

  for (int k0 = 0; k0 < 1024; k0 += 64) {
#pragma unroll
    for (int i = 0; i < 4; ++i) {
      const int r = r0 + i * 8;
      GLD(gaB + (size_t)r * 1024 + k0, As + r * 64);
      GLD(gbB + (size_t)r * 1024 + k0, Bs + r * 64);
    }
    __syncthreads();
#pragma unroll
    for (int kk = 0; kk < 2; ++kk) {
      bf16x8 a[4], b[4];
#pragma unroll
      for (int mi = 0; mi < 4; ++mi)
        a[mi] = *(const bf16x8*)(As + (wm + mi * 16 + l15) * 64 + ((kk * 4 + g) ^ sw) * 8);
#pragma unroll
      for (int ni = 0; ni < 4; ++ni)
        b[ni] = *(const bf16x8*)(Bs + (wn + ni * 16 + l15) * 64 + ((kk * 4 + g) ^ sw) * 8);
#pragma unroll
      for (int mi = 0; mi < 4; ++mi)
#pragma unroll
        for (int ni = 0; ni < 4; ++ni)
          acc[mi][ni] = __builtin_amdgcn_mfma_f32_16x16x32_bf16(a[mi], b[ni], acc[mi][ni], 0, 0, 0);
    }
    __syncthreads();
  }

  const int rb = (lane >> 4) * 4;

  if (z != 2) {
#pragma unroll
    for (int mi = 0; mi < 4; ++mi) {
#pragma unroll
      for (int r = 0; r < 4; ++r) {
        const int row = m0 + wm + mi * 16 + rb + r;
        const int bb = row >> 11, s = row & 2047;
#pragma unroll
        for (int ni = 0; ni < 4; ++ni) {
          const int col = n0 + wn + ni * 16 + l15;
          const int hh = col >> 6, d = col & 63;
          C[((size_t)(bb * NH + hh) * SEQ + s) * DK + d] = bf16_rne(acc[mi][ni][r]);
        }
      }
    }
  } else {
    // V: transposed write via LDS (tile covers heads (n0>>6)+{0,1})
    const int bb = m0 >> 11;
    const int s0 = m0 & 2047;
    u16* const T = sh;   // 64 x 136, XOR-swizzled along s
    const int dRd  = tid >> 2;
    const int cbRd = (tid & 3) * 32;
    const int swzR = ((dRd >> 3) & 7) << 3;
#pragma unroll
    for (int p = 0; p < 2; ++p) {
      if ((w & 1) == p) {
#pragma unroll
        for (int mi = 0; mi < 4; ++mi)
#pragma unroll
          for (int r = 0; r < 4; ++r) {
            const int s_local = wm + mi * 16 + rb + r;
#pragma unroll
            for (int ni = 0; ni < 4; ++ni) {
              const int d = ni * 16 + l15;
              T[d * 136 + (s_local ^ (((d >> 3) & 7) << 3))] = bf16_rne(acc[mi][ni][r]);
            }
          }
      }
      __syncthreads();
      u16* dst = C + ((size_t)(bb * NH + (n0 >> 6) + p) * DK + dRd) * SEQ + s0 + cbRd;
#pragma unroll
      for (int k = 0; k < 4; ++k) {
        int4 v = *(const int4*)(T + dRd * 136 + ((cbRd + 8 * k) ^ swzR));
        *(int4*)(dst + 8 * k) = v;
      }
      __syncthreads();
    }
  }
}

// ---------------------------------------------------------------- out GEMM
// (exact R12: BK=64)
__global__ __launch_bounds__(256) void gemm_out(
    const u16* __restrict__ A, const u16* __restrict__ Wt, float* __restrict__ C)
{
  __shared__ __align__(16) u16 sh[16384];  // As 8192 + Bs 8192 (BK=64)
  u16* const As = sh;
  u16* const Bs = sh + 8192;

  const int tid  = threadIdx.x;
  const int lane = tid & 63;
  const int w    = tid >> 6;
  const int wm   = (w >> 1) * 64;
  const int wn   = (w & 1) * 64;
  const int m0   = blockIdx.x * 128;
  const int n0   = blockIdx.y * 128;

  const int l15  = lane & 15;
  const int g    = lane >> 4;
  const int sw   = l15 & 7;

  const int lrow = lane >> 3;
  const int lcol = ((lane & 7) ^ lrow) * 8;

  const int r0 = w * 32;
  const u16* const gaB = A  + (size_t)(m0 + lrow) * 1024 + lcol;
  const u16* const gbB = Wt + (size_t)(n0 + lrow) * 1024 + lcol;

  f32x4 acc[4][4] = {};

  for (int k0 = 0; k0 < 1024; k0 += 64) {
#pragma unroll
    for (int i = 0; i < 4; ++i) {
      const int r = r0 + i * 8;
      GLD(gaB + (size_t)r * 1024 + k0, As + r * 64);
      GLD(gbB + (size_t)r * 1024 + k0, Bs + r * 64);
    }
    __syncthreads();
#pragma unroll
    for (int kk = 0; kk < 2; ++kk) {
      bf16x8 a[4], b[4];
#pragma unroll
      for (int mi = 0; mi < 4; ++mi)
        a[mi] = *(const bf16x8*)(As + (wm + mi * 16 + l15) * 64 + ((kk * 4 + g) ^ sw) * 8);
#pragma unroll
      for (int ni = 0; ni < 4; ++ni)
        b[ni] = *(const bf16x8*)(Bs + (wn + ni * 16 + l15) * 64 + ((kk * 4 + g) ^ sw) * 8);
#pragma unroll
      for (int mi = 0; mi < 4; ++mi)
#pragma unroll
        for (int ni = 0; ni < 4; ++ni)
          acc[mi][ni] = __builtin_amdgcn_mfma_f32_16x16x32_bf16(a[mi], b[ni], acc[mi][ni], 0, 0, 0);
    }
    __syncthreads();
  }

  const int rb = (lane >> 4) * 4;
#pragma unroll
  for (int mi = 0; mi < 4; ++mi) {
#pragma unroll
    for (int r = 0; r < 4; ++r) {
      const int row = m0 + wm + mi * 16 + rb + r;
#pragma unroll
      for (int ni = 0; ni < 4; ++ni) {
        const int col = n0 + wn + ni * 16 + l15;
        C[(size_t)row * 1024 + col] = acc[mi][ni][r];
      }
    }
  }
}

// ---------------------------------------------------------------- attention
// (exact R12: paired 64-key sub-tiles, double-buffered, one barrier per pair;
// no-max base-2 softmax, in-register P, P*ones row-sum on MFMA)
__global__ __launch_bounds__(256) void attn64(
    const u16* __restrict__ Q, const u16* __restrict__ K, const u16* __restrict__ VT,
    u16* __restrict__ O)
{
  const int b   = blockIdx.x;              // 0..511
  const int xcd = b & 7;
  const int bh  = xcd * 8 + ((b >> 3) & 7);
  const int it  = b >> 6;                  // 0..7

  const int tid  = threadIdx.x;
  const int lane = tid & 63;
  const int w    = tid >> 6;

  const u16* Qp = Q  + (size_t)bh * SEQ * DK;
  const u16* Kp = K  + (size_t)bh * SEQ * DK;
  const u16* Vp = VT + (size_t)bh * DK * SEQ;   // [d][s]

  __shared__ __align__(16) u16 Ks[2][2][64 * 64];  // [buf][sub][key][d]
  __shared__ __align__(16) u16 Vs[2][2][64 * 64];  // [buf][sub][d][key]

  const int l15 = lane & 15;
  const int g   = lane >> 4;
  const int g8  = g * 8;

  const int r_  = tid >> 3;                         // 0..31
  const int cS_ = ((tid & 7) ^ (r_ & 7)) * 8;       // u16 col offset in row
  const u16* kgA = Kp + (size_t)r_ * DK + cS_;          // + tau*64*DK
  const u16* kgB = Kp + (size_t)(r_ + 32) * DK + cS_;   // (r_+32)&7 == r_&7
  const u16* vgA = Vp + (size_t)r_ * SEQ + cS_;         // + tau*64
  const u16* vgB = Vp + (size_t)(r_ + 32) * SEQ + cS_;

  const int sS0 = ( g      ^ (l15 & 7)) * 8;
  const int sS1 = ((4 + g) ^ (l15 & 7)) * 8;

  const int b_ = bh >> 4, h_ = bh & 15;

  bf16x8 vone;
#pragma unroll
  for (int i = 0; i < 8; ++i) vone[i] = (short)0x3F80;   // bf16 1.0

  for (int pass = 0; pass < 2; ++pass) {
    const int qt = pass ? 15 - it : it;   // 128-row q-tile index, 0..15
    const int qw = qt * 128 + w * 32;     // wave's 32 rows

    bf16x8 qf[2][2];
#pragma unroll
    for (int j = 0; j < 2; ++j)
#pragma unroll
      for (int kk = 0; kk < 2; ++kk)
        qf[j][kk] = *(const bf16x8*)(Qp + (size_t)(qw + j * 16 + l15) * DK + kk * 32 + g8);

    f32x4 o[2][4] = {};                   // per group: O[16 q][64 d], C-layout
    f32x4 osum[2] = {};                   // row-sums via P*ones (same layout)

    __syncthreads();                      // prev pass's readers done (parity varies)
    // prologue: stage pair 0 (tiles 0,1) -> buf 0
#pragma unroll
    for (int u = 0; u < 2; ++u) {
      const size_t ko = (size_t)u * 64 * DK;
      const int    vo = u * 64;
      GLD(kgA + ko, &Ks[0][u][0] + tid * 8);
      GLD(kgB + ko, &Ks[0][u][2048] + tid * 8);
      GLD(vgA + vo, &Vs[0][u][0] + tid * 8);
      GLD(vgB + vo, &Vs[0][u][2048] + tid * 8);
    }

    for (int p2 = 0; p2 <= qt; ++p2) {
      __syncthreads();                 // pair p2 landed; other buf's readers done
      const int cb = p2 & 1;
      if (p2 < qt) {                   // stage pair p2+1 into the other buffer
        const int nb = cb ^ 1;
#pragma unroll
        for (int u = 0; u < 2; ++u) {
          const int tau = 2 * (p2 + 1) + u;
          const size_t ko = (size_t)tau * 64 * DK;
          const int    vo = tau * 64;
          GLD(kgA + ko, &Ks[nb][u][0] + tid * 8);
          GLD(kgB + ko, &Ks[nb][u][2048] + tid * 8);
          GLD(vgA + vo, &Vs[nb][u][0] + tid * 8);
          GLD(vgB + vo, &Vs[nb][u][2048] + tid * 8);
        }
      }

#pragma unroll
      for (int u = 0; u < 2; ++u) {
        const int tau = 2 * p2 + u;
        if (64 * tau >= qw + 32) continue;   // sub-tile beyond wave's diagonal

        const u16* const ksb = &Ks[cb][u][0];
        const u16* const vsb = &Vs[cb][u][0];

        // ---- S^T = K . Q^T, both row-groups sharing the K frags
        f32x4 st[2][4] = {};
#pragma unroll
        for (int kk = 0; kk < 2; ++kk) {
          const int so = kk ? sS1 : sS0;
#pragma unroll
          for (int mt = 0; mt < 4; ++mt) {
            const bf16x8 kf = *(const bf16x8*)(ksb + (mt * 16 + l15) * 64 + so);
            st[0][mt] = __builtin_amdgcn_mfma_f32_16x16x32_bf16(kf, qf[0][kk], st[0][mt], 0, 0, 0);
            st[1][mt] = __builtin_amdgcn_mfma_f32_16x16x32_bf16(kf, qf[1][kk], st[1][mt], 0, 0, 0);
          }
        }

        bf16x8 pa[2][2];                 // in-register P fragments for PV
#pragma unroll
        for (int j = 0; j < 2; ++j) {
          const int qg = qw + j * 16;
          if (qg <= 64 * tau + 48) {     // diagonal overlap: apply causal mask
            const int qrow = qg + l15;
#pragma unroll
            for (int mt = 0; mt < 4; ++mt)
#pragma unroll
              for (int r = 0; r < 4; ++r)
                if (64 * tau + mt * 16 + g * 4 + r > qrow) st[j][mt][r] = -1e30f;
          }

          // ---- P = 2^S (no max subtraction needed in f32 base-2)
          unsigned pkx[4], pky[4];
#pragma unroll
          for (int mt = 0; mt < 4; ++mt) {
            float p0 = exp2_raw(st[j][mt][0]);
            float p1 = exp2_raw(st[j][mt][1]);
            float p2_ = exp2_raw(st[j][mt][2]);
            float p3 = exp2_raw(st[j][mt][3]);
            pkx[mt] = cvt_pk_bf16(p0, p1);
            pky[mt] = cvt_pk_bf16(p2_, p3);
          }
          pa[j][0] = pfrag(pkx[0], pky[0], pkx[1], pky[1]);
          pa[j][1] = pfrag(pkx[2], pky[2], pkx[3], pky[3]);
        }

        // ---- O += P . V ; osum += P . ones  (all fragments in registers)
#pragma unroll
        for (int kk = 0; kk < 2; ++kk) {
          const int so = kk ? sS1 : sS0;
          osum[0] = __builtin_amdgcn_mfma_f32_16x16x32_bf16(pa[0][kk], vone, osum[0], 0, 0, 0);
          osum[1] = __builtin_amdgcn_mfma_f32_16x16x32_bf16(pa[1][kk], vone, osum[1], 0, 0, 0);
#pragma unroll
          for (int nt = 0; nt < 4; ++nt) {
            const bf16x8 vv = *(const bf16x8*)(vsb + (nt * 16 + l15) * 64 + so);
            o[0][nt] = __builtin_amdgcn_mfma_f32_16x16x32_bf16(pa[0][kk], vv, o[0][nt], 0, 0, 0);
            o[1][nt] = __builtin_amdgcn_mfma_f32_16x16x32_bf16(pa[1][kk], vv, o[1][nt], 0, 0, 0);
          }
        }
      }
    }

    // epilogue: O[q][d] / l  -> Ob[b][s][h*64+d]
    // osum[j][r] is the denominator for row g*4+r in THIS lane (no shuffle).
#pragma unroll
    for (int j = 0; j < 2; ++j) {
#pragma unroll
      for (int r = 0; r < 4; ++r) {
        const float inv = 1.0f / osum[j][r];
        const int   s   = qw + j * 16 + g * 4 + r;
#pragma unroll
        for (int nt = 0; nt < 4; ++nt) {
          const int d = nt * 16 + l15;
          O[((size_t)b_ * SEQ + s) * EMB + h_ * DK + d] = bf16_rne(o[j][nt][r] * inv);
        }
      }
    }
  }
}

// ---------------------------------------------------------------- launch
extern "C" void kernel_launch(void* const* d_in, const int* in_sizes, int n_in,
                              void* d_out, int out_size, void* d_ws, size_t ws_size,
                              hipStream_t stream) {
  (void)in_sizes; (void)n_in;
  const float* x  = (const float*)d_in[0];
  const float* WQ = (const float*)d_in[1];
  const float* WK = (const float*)d_in[2];
  const float* WV = (const float*)d_in[3];
  const float* WO = (const float*)d_in[4];
  float* out = (float*)d_out;

  const size_t MTOK = (size_t)4 * SEQ;        // 8192 rows
  const size_t NTOK = MTOK * EMB;             // 8,388,608 elements
  const size_t NW   = (size_t)EMB * EMB;      // 1,048,576 elements

  const size_t NEEDED = 4 * NTOK * sizeof(u16);   // 64 MiB: Q,K,VT,Ob (bf16)
  if (ws_size < NEEDED) {
    fill_sig<<<dim3((out_size + 255) / 256), 256, 0, stream>>>(out, out_size);
    return;
  }

  u16* ws  = (u16*)d_ws;
  u16* Qb  = ws;
  u16* Kb  = Qb + NTOK;
  u16* VTb = Kb + NTOK;
  u16* Ob  = VTb + NTOK;
  // scratch in dead regions:
  u16* xb  = (u16*)d_out;   // d_out (32MB f32) unused until gemm_out; xb = 16MB
  u16* WQt = Ob;            // Ob not written until attn64
  u16* WKt = WQt + NW;
  u16* WVt = WKt + NW;

  const size_t EXT = NW * sizeof(u16);    // 2 MiB for WOt beyond the 64 MiB
  if (ws_size >= NEEDED + EXT) {
    // extended path: WOt lives past the 64 MiB region (never overwritten),
    // so tcvt1 folds into prep and gemm_out follows attn64 directly.
    u16* WOt = Ob + NTOK;                 // == ws + 64 MiB
    prep<<<dim3(4096 + 768 + 256), 256, 0, stream>>>(
        x, xb, WQ, WK, WV, WQt, WKt, WVt, WO, WOt);
    gemm_qkv<<<dim3(MTOK / 128, EMB / 128, 3), 256, 0, stream>>>(
        xb, WQt, WKt, WVt, Qb, Kb, VTb);
    attn64<<<dim3(512), 256, 0, stream>>>(Qb, Kb, VTb, Ob);
    gemm_out<<<dim3(MTOK / 128, EMB / 128), 256, 0, stream>>>(Ob, WOt, out);
  } else {
    // legacy path (exact R14): WOt aliases Qb (dead after attn64)
    u16* WOt = Qb;
    prep<<<dim3(4096 + 768), 256, 0, stream>>>(
        x, xb, WQ, WK, WV, WQt, WKt, WVt, WO, WOt /*unused*/);
    gemm_qkv<<<dim3(MTOK / 128, EMB / 128, 3), 256, 0, stream>>>(
        xb, WQt, WKt, WVt, Qb, Kb, VTb);
    attn64<<<dim3(512), 256, 0, stream>>>(Qb, Kb, VTb, Ob);
    tcvt1<<<dim3(16, 16), 256, 0, stream>>>(WO, WOt);
    gemm_out<<<dim3(MTOK / 128, EMB / 128), 256, 0, stream>>>(Ob, WOt, out);
  }
}